// Round 4
// baseline (1394.591 us; speedup 1.0000x reference)
//
#include <hip/hip_runtime.h>
#include <math.h>

#define NPTS 8192
#define NPOINT 1024
#define NSAMPLE 32

// ---------------------------------------------------------------------------
// DPP max-reduce step on a packed u64 (value,index) key. VALU-only cross-lane
// (no ds_permute): 2x v_mov_dpp + v_cmp_lt_u64 + 2x v_cndmask per step.
// bound_ctrl=true => lanes with invalid DPP source read 0 = identity for max.
// ---------------------------------------------------------------------------
template <int CTRL>
__device__ __forceinline__ unsigned long long dpp_max_step(unsigned long long key) {
  int lo = (int)(unsigned)key;
  int hi = (int)(unsigned)(key >> 32);
  int slo = __builtin_amdgcn_update_dpp(0, lo, CTRL, 0xF, 0xF, true);
  int shi = __builtin_amdgcn_update_dpp(0, hi, CTRL, 0xF, 0xF, true);
  unsigned long long o =
      ((unsigned long long)(unsigned)shi << 32) | (unsigned)slo;
  return (o > key) ? o : key;
}

// ---------------------------------------------------------------------------
// FPS v4: one block per batch, 512 threads, 16 points/thread in registers.
// v3->v4: 32pts/thread @256thr spilled px/py/pz/dist (128 regs) to AGPRs
// (VGPR_Count=84 < 128) and ran 1 wave/SIMD (zero latency hiding). 16/thread
// fits in arch VGPRs and gives 2 waves/SIMD so DPP/barrier/centroid-load
// latency overlaps the other wave's distance loop.
// Bit-exact selection math vs numpy: contract off, ((dx*dx+dy*dy)+dz*dz),
// min-accumulate, argmax with first-occurrence tie-break (u64 key, DPP max).
// ---------------------------------------------------------------------------
__global__ __launch_bounds__(512, 2) void fps_kernel(const float* __restrict__ xyz,
                                                     float* __restrict__ new_xyz) {
#pragma clang fp contract(off)
  const int b = blockIdx.x;
  const int tid = threadIdx.x;
  const float* xp = xyz + (size_t)b * 3 * NPTS;
  float px[16], py[16], pz[16], dist[16];
#pragma unroll
  for (int i = 0; i < 16; ++i) {
    int n = tid + 512 * i;              // strided ownership: coalesced loads
    px[i] = xp[n];
    py[i] = xp[NPTS + n];
    pz[i] = xp[2 * NPTS + n];
    dist[i] = 1e10f;                    // same f32 value as np.full(1e10)
  }
  __shared__ unsigned long long red[2][8];   // parity double-buffered keys
  float* outp = new_xyz + (size_t)b * NPOINT * 3;
  // first centroid is point 0; every thread reads it (broadcast, L2-hot)
  float cx = xp[0], cy = xp[NPTS], cz = xp[2 * NPTS];
  if (tid == 0) { outp[0] = cx; outp[1] = cy; outp[2] = cz; }
  for (int s = 1; s < NPOINT; ++s) {
    float bv = -1.0f;
    int bI = 0;
#pragma unroll
    for (int i = 0; i < 16; ++i) {
      float dx = px[i] - cx;
      float dy = py[i] - cy;
      float dz = pz[i] - cz;
      float d = dx * dx + dy * dy + dz * dz;   // contract off: exact np order
      float dm = fminf(dist[i], d);
      dist[i] = dm;
      if (dm > bv) { bv = dm; bI = i; }        // strict >: first-occurrence
    }
    int bi = tid + (bI << 9);           // global point index (n = tid + 512*i)
    // bv >= 0 here (min of squared dists), so float bits are order-monotonic.
    // Key: high32 = value bits, low32 = 8191-bi => max key = max val, min idx.
    unsigned long long key =
        ((unsigned long long)__float_as_uint(bv) << 32) |
        (unsigned)(8191 - bi);
    // wave64 DPP reduce (canonical GCN sequence); result lands in lane 63
    key = dpp_max_step<0x111>(key);     // row_shr:1
    key = dpp_max_step<0x112>(key);     // row_shr:2
    key = dpp_max_step<0x114>(key);     // row_shr:4
    key = dpp_max_step<0x118>(key);     // row_shr:8
    key = dpp_max_step<0x142>(key);     // row_bcast:15 (row r -> row r+1)
    key = dpp_max_step<0x143>(key);     // row_bcast:31 (lane31 -> upper half)
    unsigned wlo = (unsigned)__builtin_amdgcn_readlane((int)(unsigned)key, 63);
    unsigned whi =
        (unsigned)__builtin_amdgcn_readlane((int)(unsigned)(key >> 32), 63);
    unsigned long long wkey = ((unsigned long long)whi << 32) | wlo;
    if ((tid & 63) == 0) red[s & 1][tid >> 6] = wkey;
    __syncthreads();                    // the only barrier per iteration
    unsigned long long k0 = red[s & 1][0];
    unsigned long long k1 = red[s & 1][1];
    unsigned long long k2 = red[s & 1][2];
    unsigned long long k3 = red[s & 1][3];
    unsigned long long k4 = red[s & 1][4];
    unsigned long long k5 = red[s & 1][5];
    unsigned long long k6 = red[s & 1][6];
    unsigned long long k7 = red[s & 1][7];
    unsigned long long ka = (k0 > k1) ? k0 : k1;
    unsigned long long kb = (k2 > k3) ? k2 : k3;
    unsigned long long kc = (k4 > k5) ? k4 : k5;
    unsigned long long kd = (k6 > k7) ? k6 : k7;
    unsigned long long ke = (ka > kb) ? ka : kb;
    unsigned long long kf = (kc > kd) ? kc : kd;
    unsigned long long km = (ke > kf) ? ke : kf;
    int gi = 8191 - (int)(unsigned)(km & 0xFFFFFFFFull);
    // all threads fetch the centroid themselves: 3 same-address loads
    // (single transaction each, L2-hot 96KB working set)
    cx = xp[gi];
    cy = xp[NPTS + gi];
    cz = xp[2 * NPTS + gi];
    if (tid == 0) { outp[3 * s] = cx; outp[3 * s + 1] = cy; outp[3 * s + 2] = cz; }
  }
}

// ---------------------------------------------------------------------------
// Ball query: one wave per center. Replicates the reference's expanded
// sq = |a|^2 + |b|^2 - 2 a.b (contract off) and first-32-by-index semantics.
// ---------------------------------------------------------------------------
__global__ __launch_bounds__(256) void bq_kernel(const float* __restrict__ xyz,
                                                 const float* __restrict__ new_xyz,
                                                 int* __restrict__ idx_out) {
#pragma clang fp contract(off)
  __shared__ int slots[4][NSAMPLE];
  const int tid = threadIdx.x;
  const int wv = tid >> 6, lane = tid & 63;
  const int gc = blockIdx.x * 4 + wv;   // global center 0..4095
  const int b = gc >> 10;
  const float* xp = xyz + (size_t)b * 3 * NPTS;
  const float* cp = new_xyz + (size_t)gc * 3;
  const float cx = cp[0], cy = cp[1], cz = cp[2];
  const float asq = (cx * cx + cy * cy) + cz * cz;
  int cnt = 0;
  for (int base = 0; base < NPTS; base += 64) {
    int n = base + lane;
    float x = xp[n], y = xp[NPTS + n], z = xp[2 * NPTS + n];
    float bsq = (x * x + y * y) + z * z;
    float ab = (x * cx + y * cy) + z * cz;
    float sq = (asq + bsq) - 2.0f * ab;
    bool inc = !(sq > 0.01f);           // same f32 threshold as reference
    unsigned long long mk = __ballot(inc);
    int pos = cnt + (int)__popcll(mk & ((1ull << lane) - 1ull));
    if (inc && pos < NSAMPLE) slots[wv][pos] = n;
    cnt += (int)__popcll(mk);
    if (cnt >= NSAMPLE) break;          // wave-uniform
  }
  __syncthreads();
  if (lane < NSAMPLE) {
    int first = slots[wv][0];           // >=1 hit guaranteed (center itself)
    int v = (lane < cnt) ? slots[wv][lane] : first;
    idx_out[(size_t)gc * NSAMPLE + lane] = v;
  }
}

// ---------------------------------------------------------------------------
// Setup: transpose w3 -> w3t[c][o3] for coalesced per-lane loads, and fold
// BN (+conv bias) into per-channel scale/shift.
// ---------------------------------------------------------------------------
__global__ __launch_bounds__(256) void setup_kernel(
    const float* __restrict__ w3,
    const float* __restrict__ b1, const float* __restrict__ g1, const float* __restrict__ t1,
    const float* __restrict__ m1, const float* __restrict__ v1,
    const float* __restrict__ b2, const float* __restrict__ g2, const float* __restrict__ t2,
    const float* __restrict__ m2, const float* __restrict__ v2,
    const float* __restrict__ b3, const float* __restrict__ g3, const float* __restrict__ t3,
    const float* __restrict__ m3, const float* __restrict__ v3,
    float* __restrict__ w3t, float* __restrict__ scsh) {
  int tid = threadIdx.x;
  for (int i = tid; i < 8192; i += 256) {
    int o = i >> 6, c = i & 63;
    w3t[c * 128 + o] = w3[i];
  }
  if (tid < 64) {
    float s = g1[tid] / sqrtf(v1[tid] + 1e-5f);
    scsh[tid] = s;
    scsh[64 + tid] = (b1[tid] - m1[tid]) * s + t1[tid];
    float s2 = g2[tid] / sqrtf(v2[tid] + 1e-5f);
    scsh[128 + tid] = s2;
    scsh[192 + tid] = (b2[tid] - m2[tid]) * s2 + t2[tid];
  }
  if (tid < 128) {
    float s3 = g3[tid] / sqrtf(v3[tid] + 1e-5f);
    scsh[256 + tid] = s3;
    scsh[384 + tid] = (b3[tid] - m3[tid]) * s3 + t3[tid];
  }
}

// ---------------------------------------------------------------------------
// Fused gather + MLP(6->64->64->128, BN+ReLU) + max over 32 samples.
// Block = 256 threads = 8 centers x 32 samples. Activations live in one
// 64KB LDS buffer, XOR-swizzled at float4 granularity (conflict-free at the
// b128 bank floor). L1/L2 use (center,sample) mapping (own-row, no barrier);
// L3 uses (center,channel-lane) mapping so the k-loop folds into a register
// max (no cross-lane butterfly).
// ---------------------------------------------------------------------------
__global__ __launch_bounds__(256, 2) void mlp_kernel(
    const float* __restrict__ xyz, const float* __restrict__ points,
    const float* __restrict__ new_xyz, const int* __restrict__ idx,
    const float* __restrict__ w1, const float* __restrict__ w2,
    const float* __restrict__ w3t, const float* __restrict__ scsh,
    float* __restrict__ out) {
  __shared__ float act[256 * 64];       // exactly 64 KB -> 2 blocks/CU
  float4* act4 = (float4*)act;
  const int tid = threadIdx.x;
  const int s0 = blockIdx.x * 8;
  const int b = s0 >> 10;               // 8 | 1024 -> uniform per block
  const int g = tid >> 5;               // center within block
  const int k = tid & 31;               // sample (phase A) / channel lane (L3)
  const int gc = s0 + g;
  const float* xp = xyz + (size_t)b * 3 * NPTS;
  const float* pp = points + (size_t)b * 3 * NPTS;
  const float* cp = new_xyz + (size_t)gc * 3;
  const int n = idx[(size_t)gc * NSAMPLE + k];
  float f0 = xp[n] - cp[0];
  float f1 = xp[NPTS + n] - cp[1];
  float f2 = xp[2 * NPTS + n] - cp[2];
  float f3 = pp[n];
  float f4 = pp[NPTS + n];
  float f5 = pp[2 * NPTS + n];
  const float* sc1 = scsh;        const float* sh1 = scsh + 64;
  const float* sc2 = scsh + 128;  const float* sh2 = scsh + 192;
  const float* sc3 = scsh + 256;  const float* sh3 = scsh + 384;
  const int row = tid;

  // ---- L1: x1[o] = relu(bn(W1 @ f)) -> LDS (own row, swizzled float4) ----
#pragma unroll
  for (int oc = 0; oc < 16; ++oc) {
    float va[4];
#pragma unroll
    for (int jj = 0; jj < 4; ++jj) {
      int o = oc * 4 + jj;
      const float* wr = w1 + o * 6;     // wave-uniform -> scalar loads
      float a = f0 * wr[0] + f1 * wr[1] + f2 * wr[2] +
                f3 * wr[3] + f4 * wr[4] + f5 * wr[5];
      va[jj] = fmaxf(a * sc1[o] + sh1[o], 0.f);
    }
    act4[row * 16 + (oc ^ (row & 15))] = make_float4(va[0], va[1], va[2], va[3]);
  }

  // ---- L2: own-row contraction, 64 accumulators, uniform scalar weights ----
  float acc[64];
#pragma unroll
  for (int o = 0; o < 64; ++o) acc[o] = 0.f;
  for (int cc = 0; cc < 16; ++cc) {     // dynamic: LDS handles dynamic index
    float4 av = act4[row * 16 + (cc ^ (row & 15))];
#pragma unroll
    for (int o = 0; o < 64; ++o) {
      const float* wr = w2 + o * 64 + cc * 4;  // wave-uniform address
      acc[o] += av.x * wr[0] + av.y * wr[1] + av.z * wr[2] + av.w * wr[3];
    }
  }
  // bn+relu, overwrite own row with x2 (no cross-thread x1 readers)
#pragma unroll
  for (int oc = 0; oc < 16; ++oc) {
    float va[4];
#pragma unroll
    for (int jj = 0; jj < 4; ++jj) {
      int o = oc * 4 + jj;
      va[jj] = fmaxf(acc[o] * sc2[o] + sh2[o], 0.f);
    }
    act4[row * 16 + (oc ^ (row & 15))] = make_float4(va[0], va[1], va[2], va[3]);
  }
  __syncthreads();                      // x2 visible to whole block

  // ---- L3 + max over k: lane j owns channel o3 = p*32+j ----
  const int j = k;
  const int sb = gc & 1023;
  for (int p = 0; p < 4; ++p) {
    int o3 = p * 32 + j;
    float wreg[64];
#pragma unroll
    for (int c = 0; c < 64; ++c) wreg[c] = w3t[c * 128 + o3];  // coalesced
    float osc = sc3[o3], osh = sh3[o3];
    float vmax = 0.f;                   // post-relu values are >= 0
    for (int kk = 0; kk < 32; ++kk) {
      int r2 = g * 32 + kk;             // uniform within 32-lane group
      float a0 = 0.f, a1 = 0.f, a2 = 0.f, a3 = 0.f;
#pragma unroll
      for (int cc = 0; cc < 16; cc += 4) {
        float4 u0 = act4[r2 * 16 + ((cc + 0) ^ (r2 & 15))];  // broadcast b128
        float4 u1 = act4[r2 * 16 + ((cc + 1) ^ (r2 & 15))];
        float4 u2 = act4[r2 * 16 + ((cc + 2) ^ (r2 & 15))];
        float4 u3 = act4[r2 * 16 + ((cc + 3) ^ (r2 & 15))];
        a0 += u0.x * wreg[4*cc+0]  + u0.y * wreg[4*cc+1]  + u0.z * wreg[4*cc+2]  + u0.w * wreg[4*cc+3];
        a1 += u1.x * wreg[4*cc+4]  + u1.y * wreg[4*cc+5]  + u1.z * wreg[4*cc+6]  + u1.w * wreg[4*cc+7];
        a2 += u2.x * wreg[4*cc+8]  + u2.y * wreg[4*cc+9]  + u2.z * wreg[4*cc+10] + u2.w * wreg[4*cc+11];
        a3 += u3.x * wreg[4*cc+12] + u3.y * wreg[4*cc+13] + u3.z * wreg[4*cc+14] + u3.w * wreg[4*cc+15];
      }
      float x3 = (a0 + a1) + (a2 + a3);
      vmax = fmaxf(vmax, fmaxf(x3 * osc + osh, 0.f));
    }
    out[((size_t)b * 128 + o3) * 1024 + sb] = vmax;   // (B,128,1024)
  }
}

// ---------------------------------------------------------------------------
extern "C" void kernel_launch(void* const* d_in, const int* in_sizes, int n_in,
                              void* d_out, int out_size, void* d_ws, size_t ws_size,
                              hipStream_t stream) {
  (void)in_sizes; (void)n_in; (void)out_size; (void)ws_size;
  const float* xyz    = (const float*)d_in[0];
  const float* points = (const float*)d_in[1];
  const float* w1 = (const float*)d_in[2];
  const float* b1 = (const float*)d_in[3];
  const float* g1 = (const float*)d_in[4];
  const float* t1 = (const float*)d_in[5];
  const float* m1 = (const float*)d_in[6];
  const float* v1 = (const float*)d_in[7];
  const float* w2 = (const float*)d_in[8];
  const float* b2 = (const float*)d_in[9];
  const float* g2 = (const float*)d_in[10];
  const float* t2 = (const float*)d_in[11];
  const float* m2 = (const float*)d_in[12];
  const float* v2 = (const float*)d_in[13];
  const float* w3 = (const float*)d_in[14];
  const float* b3 = (const float*)d_in[15];
  const float* g3 = (const float*)d_in[16];
  const float* t3 = (const float*)d_in[17];
  const float* m3 = (const float*)d_in[18];
  const float* v3 = (const float*)d_in[19];

  float* wsf = (float*)d_ws;
  float* new_xyz = wsf;                         // 4*1024*3   = 12288 f
  int*   idx     = (int*)(wsf + 12288);         // 4*1024*32  = 131072 i
  float* w3t     = wsf + 12288 + 131072;        // 64*128     = 8192 f
  float* scsh    = w3t + 8192;                  // 512 f
  float* out     = (float*)d_out;               // (4,128,1024) f32

  hipLaunchKernelGGL(setup_kernel, dim3(1), dim3(256), 0, stream,
                     w3, b1, g1, t1, m1, v1, b2, g2, t2, m2, v2,
                     b3, g3, t3, m3, v3, w3t, scsh);
  hipLaunchKernelGGL(fps_kernel, dim3(4), dim3(512), 0, stream, xyz, new_xyz);
  hipLaunchKernelGGL(bq_kernel, dim3(1024), dim3(256), 0, stream,
                     xyz, new_xyz, idx);
  hipLaunchKernelGGL(mlp_kernel, dim3(512), dim3(256), 0, stream,
                     xyz, points, new_xyz, idx, w1, w2, w3t, scsh, out);
}

// Round 5
// 1293.938 us; speedup vs baseline: 1.0778x; 1.0778x over previous
//
#include <hip/hip_runtime.h>
#include <math.h>

#define NPTS 8192
#define NPOINT 1024
#define NSAMPLE 32

typedef float v2f __attribute__((ext_vector_type(2)));

// ---------------------------------------------------------------------------
// DPP max-reduce step on a packed u64 (value,index) key. VALU-only cross-lane
// (no ds_permute): 2x v_mov_dpp + v_cmp_lt_u64 + 2x v_cndmask per step.
// bound_ctrl=true => lanes with invalid DPP source read 0 = identity for max.
// ---------------------------------------------------------------------------
template <int CTRL>
__device__ __forceinline__ unsigned long long dpp_max_step(unsigned long long key) {
  int lo = (int)(unsigned)key;
  int hi = (int)(unsigned)(key >> 32);
  int slo = __builtin_amdgcn_update_dpp(0, lo, CTRL, 0xF, 0xF, true);
  int shi = __builtin_amdgcn_update_dpp(0, hi, CTRL, 0xF, 0xF, true);
  unsigned long long o =
      ((unsigned long long)(unsigned)shi << 32) | (unsigned)slo;
  return (o > key) ? o : key;
}

// ---------------------------------------------------------------------------
// FPS v5: one block per batch, 256 threads, 32 points/thread as 16 float2
// pairs. v4 post-mortem: compiler AGPR-spills the arrays unless waves/EU=1
// frees the full 512-VGPR budget (R3 VGPR=84, R4 VGPR=48 — both spilled).
// __launch_bounds__(256,1) + float2 packed math (v_pk_add/mul_f32, IEEE-
// identical per element) halve the distance-loop issue cost.
// Bit-exact selection vs numpy: contract off, ((dx*dx+dy*dy)+dz*dz),
// min-accumulate, argmax first-occurrence (u64 key, DPP max reduce).
// ---------------------------------------------------------------------------
__global__ __launch_bounds__(256, 1) void fps_kernel(const float* __restrict__ xyz,
                                                     float* __restrict__ new_xyz) {
#pragma clang fp contract(off)
  const int b = blockIdx.x;
  const int tid = threadIdx.x;
  const float* xp = xyz + (size_t)b * 3 * NPTS;
  // pair j holds i=2j (.x, n=tid+512j) and i=2j+1 (.y, n=tid+512j+256)
  v2f px2[16], py2[16], pz2[16], d2[16];
#pragma unroll
  for (int j = 0; j < 16; ++j) {
    int n0 = tid + 512 * j;
    int n1 = n0 + 256;
    px2[j] = (v2f){xp[n0], xp[n1]};
    py2[j] = (v2f){xp[NPTS + n0], xp[NPTS + n1]};
    pz2[j] = (v2f){xp[2 * NPTS + n0], xp[2 * NPTS + n1]};
    d2[j] = (v2f){1e10f, 1e10f};        // same f32 value as np.full(1e10)
  }
  __shared__ unsigned long long red[2][4];   // parity double-buffered keys
  float* outp = new_xyz + (size_t)b * NPOINT * 3;
  // first centroid is point 0; every thread reads it (broadcast, L2-hot)
  float cx = xp[0], cy = xp[NPTS], cz = xp[2 * NPTS];
  if (tid == 0) { outp[0] = cx; outp[1] = cy; outp[2] = cz; }
  for (int s = 1; s < NPOINT; ++s) {
    const v2f cxx = (v2f){cx, cx};
    const v2f cyy = (v2f){cy, cy};
    const v2f czz = (v2f){cz, cz};
    float bv = -1.0f;
    int bI = 0;
#pragma unroll
    for (int j = 0; j < 16; ++j) {
      v2f dx = px2[j] - cxx;            // v_pk_add_f32 (neg) x2 pts
      v2f dy = py2[j] - cyy;
      v2f dz = pz2[j] - czz;
      v2f xx = dx * dx;                 // v_pk_mul_f32
      v2f yy = dy * dy;
      v2f zz = dz * dz;
      v2f d = (xx + yy) + zz;           // contract off: exact np order
      float dmx = fminf(d2[j].x, d.x);  // no pk_min_f32 on CDNA: scalar
      float dmy = fminf(d2[j].y, d.y);
      d2[j].x = dmx;
      d2[j].y = dmy;
      if (dmx > bv) { bv = dmx; bI = 2 * j; }       // i ascending => n asc
      if (dmy > bv) { bv = dmy; bI = 2 * j + 1; }   // first-occurrence kept
    }
    int bi = tid + (bI << 8);           // global point index (n = tid + 256*i)
    // bv >= 0 here (min of squared dists), so float bits are order-monotonic.
    // Key: high32 = value bits, low32 = 8191-bi => max key = max val, min idx.
    unsigned long long key =
        ((unsigned long long)__float_as_uint(bv) << 32) |
        (unsigned)(8191 - bi);
    // wave64 DPP reduce (canonical GCN sequence); result lands in lane 63
    key = dpp_max_step<0x111>(key);     // row_shr:1
    key = dpp_max_step<0x112>(key);     // row_shr:2
    key = dpp_max_step<0x114>(key);     // row_shr:4
    key = dpp_max_step<0x118>(key);     // row_shr:8
    key = dpp_max_step<0x142>(key);     // row_bcast:15 (row r -> row r+1)
    key = dpp_max_step<0x143>(key);     // row_bcast:31 (lane31 -> upper half)
    unsigned wlo = (unsigned)__builtin_amdgcn_readlane((int)(unsigned)key, 63);
    unsigned whi =
        (unsigned)__builtin_amdgcn_readlane((int)(unsigned)(key >> 32), 63);
    unsigned long long wkey = ((unsigned long long)whi << 32) | wlo;
    if ((tid & 63) == 0) red[s & 1][tid >> 6] = wkey;
    __syncthreads();                    // the only barrier per iteration
    unsigned long long k0 = red[s & 1][0];
    unsigned long long k1 = red[s & 1][1];
    unsigned long long k2 = red[s & 1][2];
    unsigned long long k3 = red[s & 1][3];
    unsigned long long ka = (k0 > k1) ? k0 : k1;
    unsigned long long kb = (k2 > k3) ? k2 : k3;
    unsigned long long km = (ka > kb) ? ka : kb;
    int gi = 8191 - (int)(unsigned)(km & 0xFFFFFFFFull);
    // all threads fetch the centroid themselves: 3 same-address loads
    // (single transaction each, L2-hot 96KB working set)
    cx = xp[gi];
    cy = xp[NPTS + gi];
    cz = xp[2 * NPTS + gi];
    if (tid == 0) { outp[3 * s] = cx; outp[3 * s + 1] = cy; outp[3 * s + 2] = cz; }
  }
}

// ---------------------------------------------------------------------------
// Ball query: one wave per center. Replicates the reference's expanded
// sq = |a|^2 + |b|^2 - 2 a.b (contract off) and first-32-by-index semantics.
// ---------------------------------------------------------------------------
__global__ __launch_bounds__(256) void bq_kernel(const float* __restrict__ xyz,
                                                 const float* __restrict__ new_xyz,
                                                 int* __restrict__ idx_out) {
#pragma clang fp contract(off)
  __shared__ int slots[4][NSAMPLE];
  const int tid = threadIdx.x;
  const int wv = tid >> 6, lane = tid & 63;
  const int gc = blockIdx.x * 4 + wv;   // global center 0..4095
  const int b = gc >> 10;
  const float* xp = xyz + (size_t)b * 3 * NPTS;
  const float* cp = new_xyz + (size_t)gc * 3;
  const float cx = cp[0], cy = cp[1], cz = cp[2];
  const float asq = (cx * cx + cy * cy) + cz * cz;
  int cnt = 0;
  for (int base = 0; base < NPTS; base += 64) {
    int n = base + lane;
    float x = xp[n], y = xp[NPTS + n], z = xp[2 * NPTS + n];
    float bsq = (x * x + y * y) + z * z;
    float ab = (x * cx + y * cy) + z * cz;
    float sq = (asq + bsq) - 2.0f * ab;
    bool inc = !(sq > 0.01f);           // same f32 threshold as reference
    unsigned long long mk = __ballot(inc);
    int pos = cnt + (int)__popcll(mk & ((1ull << lane) - 1ull));
    if (inc && pos < NSAMPLE) slots[wv][pos] = n;
    cnt += (int)__popcll(mk);
    if (cnt >= NSAMPLE) break;          // wave-uniform
  }
  __syncthreads();
  if (lane < NSAMPLE) {
    int first = slots[wv][0];           // >=1 hit guaranteed (center itself)
    int v = (lane < cnt) ? slots[wv][lane] : first;
    idx_out[(size_t)gc * NSAMPLE + lane] = v;
  }
}

// ---------------------------------------------------------------------------
// Setup: transpose w3 -> w3t[c][o3] for coalesced per-lane loads, and fold
// BN (+conv bias) into per-channel scale/shift.
// ---------------------------------------------------------------------------
__global__ __launch_bounds__(256) void setup_kernel(
    const float* __restrict__ w3,
    const float* __restrict__ b1, const float* __restrict__ g1, const float* __restrict__ t1,
    const float* __restrict__ m1, const float* __restrict__ v1,
    const float* __restrict__ b2, const float* __restrict__ g2, const float* __restrict__ t2,
    const float* __restrict__ m2, const float* __restrict__ v2,
    const float* __restrict__ b3, const float* __restrict__ g3, const float* __restrict__ t3,
    const float* __restrict__ m3, const float* __restrict__ v3,
    float* __restrict__ w3t, float* __restrict__ scsh) {
  int tid = threadIdx.x;
  for (int i = tid; i < 8192; i += 256) {
    int o = i >> 6, c = i & 63;
    w3t[c * 128 + o] = w3[i];
  }
  if (tid < 64) {
    float s = g1[tid] / sqrtf(v1[tid] + 1e-5f);
    scsh[tid] = s;
    scsh[64 + tid] = (b1[tid] - m1[tid]) * s + t1[tid];
    float s2 = g2[tid] / sqrtf(v2[tid] + 1e-5f);
    scsh[128 + tid] = s2;
    scsh[192 + tid] = (b2[tid] - m2[tid]) * s2 + t2[tid];
  }
  if (tid < 128) {
    float s3 = g3[tid] / sqrtf(v3[tid] + 1e-5f);
    scsh[256 + tid] = s3;
    scsh[384 + tid] = (b3[tid] - m3[tid]) * s3 + t3[tid];
  }
}

// ---------------------------------------------------------------------------
// Fused gather + MLP(6->64->64->128, BN+ReLU) + max over 32 samples.
// Block = 256 threads = 8 centers x 32 samples. Activations live in one
// 64KB LDS buffer, XOR-swizzled at float4 granularity (conflict-free at the
// b128 bank floor). L1/L2 use (center,sample) mapping (own-row, no barrier);
// L3 uses (center,channel-lane) mapping so the k-loop folds into a register
// max (no cross-lane butterfly).
// ---------------------------------------------------------------------------
__global__ __launch_bounds__(256, 2) void mlp_kernel(
    const float* __restrict__ xyz, const float* __restrict__ points,
    const float* __restrict__ new_xyz, const int* __restrict__ idx,
    const float* __restrict__ w1, const float* __restrict__ w2,
    const float* __restrict__ w3t, const float* __restrict__ scsh,
    float* __restrict__ out) {
  __shared__ float act[256 * 64];       // exactly 64 KB -> 2 blocks/CU
  float4* act4 = (float4*)act;
  const int tid = threadIdx.x;
  const int s0 = blockIdx.x * 8;
  const int b = s0 >> 10;               // 8 | 1024 -> uniform per block
  const int g = tid >> 5;               // center within block
  const int k = tid & 31;               // sample (phase A) / channel lane (L3)
  const int gc = s0 + g;
  const float* xp = xyz + (size_t)b * 3 * NPTS;
  const float* pp = points + (size_t)b * 3 * NPTS;
  const float* cp = new_xyz + (size_t)gc * 3;
  const int n = idx[(size_t)gc * NSAMPLE + k];
  float f0 = xp[n] - cp[0];
  float f1 = xp[NPTS + n] - cp[1];
  float f2 = xp[2 * NPTS + n] - cp[2];
  float f3 = pp[n];
  float f4 = pp[NPTS + n];
  float f5 = pp[2 * NPTS + n];
  const float* sc1 = scsh;        const float* sh1 = scsh + 64;
  const float* sc2 = scsh + 128;  const float* sh2 = scsh + 192;
  const float* sc3 = scsh + 256;  const float* sh3 = scsh + 384;
  const int row = tid;

  // ---- L1: x1[o] = relu(bn(W1 @ f)) -> LDS (own row, swizzled float4) ----
#pragma unroll
  for (int oc = 0; oc < 16; ++oc) {
    float va[4];
#pragma unroll
    for (int jj = 0; jj < 4; ++jj) {
      int o = oc * 4 + jj;
      const float* wr = w1 + o * 6;     // wave-uniform -> scalar loads
      float a = f0 * wr[0] + f1 * wr[1] + f2 * wr[2] +
                f3 * wr[3] + f4 * wr[4] + f5 * wr[5];
      va[jj] = fmaxf(a * sc1[o] + sh1[o], 0.f);
    }
    act4[row * 16 + (oc ^ (row & 15))] = make_float4(va[0], va[1], va[2], va[3]);
  }

  // ---- L2: own-row contraction, 64 accumulators, uniform scalar weights ----
  float acc[64];
#pragma unroll
  for (int o = 0; o < 64; ++o) acc[o] = 0.f;
  for (int cc = 0; cc < 16; ++cc) {     // dynamic: LDS handles dynamic index
    float4 av = act4[row * 16 + (cc ^ (row & 15))];
#pragma unroll
    for (int o = 0; o < 64; ++o) {
      const float* wr = w2 + o * 64 + cc * 4;  // wave-uniform address
      acc[o] += av.x * wr[0] + av.y * wr[1] + av.z * wr[2] + av.w * wr[3];
    }
  }
  // bn+relu, overwrite own row with x2 (no cross-thread x1 readers)
#pragma unroll
  for (int oc = 0; oc < 16; ++oc) {
    float va[4];
#pragma unroll
    for (int jj = 0; jj < 4; ++jj) {
      int o = oc * 4 + jj;
      va[jj] = fmaxf(acc[o] * sc2[o] + sh2[o], 0.f);
    }
    act4[row * 16 + (oc ^ (row & 15))] = make_float4(va[0], va[1], va[2], va[3]);
  }
  __syncthreads();                      // x2 visible to whole block

  // ---- L3 + max over k: lane j owns channel o3 = p*32+j ----
  const int j = k;
  const int sb = gc & 1023;
  for (int p = 0; p < 4; ++p) {
    int o3 = p * 32 + j;
    float wreg[64];
#pragma unroll
    for (int c = 0; c < 64; ++c) wreg[c] = w3t[c * 128 + o3];  // coalesced
    float osc = sc3[o3], osh = sh3[o3];
    float vmax = 0.f;                   // post-relu values are >= 0
    for (int kk = 0; kk < 32; ++kk) {
      int r2 = g * 32 + kk;             // uniform within 32-lane group
      float a0 = 0.f, a1 = 0.f, a2 = 0.f, a3 = 0.f;
#pragma unroll
      for (int cc = 0; cc < 16; cc += 4) {
        float4 u0 = act4[r2 * 16 + ((cc + 0) ^ (r2 & 15))];  // broadcast b128
        float4 u1 = act4[r2 * 16 + ((cc + 1) ^ (r2 & 15))];
        float4 u2 = act4[r2 * 16 + ((cc + 2) ^ (r2 & 15))];
        float4 u3 = act4[r2 * 16 + ((cc + 3) ^ (r2 & 15))];
        a0 += u0.x * wreg[4*cc+0]  + u0.y * wreg[4*cc+1]  + u0.z * wreg[4*cc+2]  + u0.w * wreg[4*cc+3];
        a1 += u1.x * wreg[4*cc+4]  + u1.y * wreg[4*cc+5]  + u1.z * wreg[4*cc+6]  + u1.w * wreg[4*cc+7];
        a2 += u2.x * wreg[4*cc+8]  + u2.y * wreg[4*cc+9]  + u2.z * wreg[4*cc+10] + u2.w * wreg[4*cc+11];
        a3 += u3.x * wreg[4*cc+12] + u3.y * wreg[4*cc+13] + u3.z * wreg[4*cc+14] + u3.w * wreg[4*cc+15];
      }
      float x3 = (a0 + a1) + (a2 + a3);
      vmax = fmaxf(vmax, fmaxf(x3 * osc + osh, 0.f));
    }
    out[((size_t)b * 128 + o3) * 1024 + sb] = vmax;   // (B,128,1024)
  }
}

// ---------------------------------------------------------------------------
extern "C" void kernel_launch(void* const* d_in, const int* in_sizes, int n_in,
                              void* d_out, int out_size, void* d_ws, size_t ws_size,
                              hipStream_t stream) {
  (void)in_sizes; (void)n_in; (void)out_size; (void)ws_size;
  const float* xyz    = (const float*)d_in[0];
  const float* points = (const float*)d_in[1];
  const float* w1 = (const float*)d_in[2];
  const float* b1 = (const float*)d_in[3];
  const float* g1 = (const float*)d_in[4];
  const float* t1 = (const float*)d_in[5];
  const float* m1 = (const float*)d_in[6];
  const float* v1 = (const float*)d_in[7];
  const float* w2 = (const float*)d_in[8];
  const float* b2 = (const float*)d_in[9];
  const float* g2 = (const float*)d_in[10];
  const float* t2 = (const float*)d_in[11];
  const float* m2 = (const float*)d_in[12];
  const float* v2 = (const float*)d_in[13];
  const float* w3 = (const float*)d_in[14];
  const float* b3 = (const float*)d_in[15];
  const float* g3 = (const float*)d_in[16];
  const float* t3 = (const float*)d_in[17];
  const float* m3 = (const float*)d_in[18];
  const float* v3 = (const float*)d_in[19];

  float* wsf = (float*)d_ws;
  float* new_xyz = wsf;                         // 4*1024*3   = 12288 f
  int*   idx     = (int*)(wsf + 12288);         // 4*1024*32  = 131072 i
  float* w3t     = wsf + 12288 + 131072;        // 64*128     = 8192 f
  float* scsh    = w3t + 8192;                  // 512 f
  float* out     = (float*)d_out;               // (4,128,1024) f32

  hipLaunchKernelGGL(setup_kernel, dim3(1), dim3(256), 0, stream,
                     w3, b1, g1, t1, m1, v1, b2, g2, t2, m2, v2,
                     b3, g3, t3, m3, v3, w3t, scsh);
  hipLaunchKernelGGL(fps_kernel, dim3(4), dim3(256), 0, stream, xyz, new_xyz);
  hipLaunchKernelGGL(bq_kernel, dim3(1024), dim3(256), 0, stream,
                     xyz, new_xyz, idx);
  hipLaunchKernelGGL(mlp_kernel, dim3(512), dim3(256), 0, stream,
                     xyz, points, new_xyz, idx, w1, w2, w3t, scsh, out);
}

// Round 6
// 1246.907 us; speedup vs baseline: 1.1184x; 1.0377x over previous
//
#include <hip/hip_runtime.h>
#include <math.h>

#define NPTS 8192
#define NPOINT 1024
#define NSAMPLE 32

typedef float v2f __attribute__((ext_vector_type(2)));

// ---------------------------------------------------------------------------
// DPP reduce steps. bound_ctrl=true: invalid-source lanes read 0, which is
// the identity for both f32-max over values >=0 and u32-max.
// ---------------------------------------------------------------------------
template <int CTRL>
__device__ __forceinline__ float dpp_fmax_step(float v) {
  int s = __builtin_amdgcn_update_dpp(0, __float_as_int(v), CTRL, 0xF, 0xF, true);
  return fmaxf(v, __int_as_float(s));
}
template <int CTRL>
__device__ __forceinline__ unsigned dpp_umax_step(unsigned v) {
  int s = __builtin_amdgcn_update_dpp(0, (int)v, CTRL, 0xF, 0xF, true);
  unsigned u = (unsigned)s;
  return (u > v) ? u : v;
}

// ---------------------------------------------------------------------------
// FPS v6: one block per batch, 256 threads, 32 points/thread as 16 float2
// pairs. R5 post-mortem: latency-bound (issue -15% gave 0 speedup), so v6
// shortens the serial chain: (a) slim wave reduce = f32-max DPP chain +
// u32-index DPP chain (exactly equivalent to the u64-key max: value bits
// monotone for >=0, ties resolved by max(8191-bi) = min index, losers
// contribute 0); (b) centroid fetch = one s_load_dwordx4 from a pre-packed
// float4 table via readfirstlane(gi) (scalar path, single wait) instead of
// 3 VMEM loads + addr calc.
// Bit-exact selection vs numpy: contract off, ((dx*dx+dy*dy)+dz*dz),
// min-accumulate, argmax first-occurrence.
// ---------------------------------------------------------------------------
__global__ __launch_bounds__(256, 1) void fps_kernel(const float4* __restrict__ xyz4,
                                                     float* __restrict__ new_xyz) {
#pragma clang fp contract(off)
  const int b = blockIdx.x;
  const int tid = threadIdx.x;
  const float4* xp4 = xyz4 + (size_t)b * NPTS;
  // pair j holds i=2j (.x, n=tid+512j) and i=2j+1 (.y, n=tid+512j+256)
  v2f px2[16], py2[16], pz2[16], d2[16];
#pragma unroll
  for (int j = 0; j < 16; ++j) {
    int n0 = tid + 512 * j;
    float4 a = xp4[n0];
    float4 c2 = xp4[n0 + 256];
    px2[j] = (v2f){a.x, c2.x};
    py2[j] = (v2f){a.y, c2.y};
    pz2[j] = (v2f){a.z, c2.z};
    d2[j] = (v2f){1e10f, 1e10f};        // same f32 value as np.full(1e10)
  }
  __shared__ unsigned long long red[2][4];   // parity double-buffered keys
  float* outp = new_xyz + (size_t)b * NPOINT * 3;
  float4 c0 = xp4[0];                   // first centroid is point 0
  float cx = c0.x, cy = c0.y, cz = c0.z;
  if (tid == 0) { outp[0] = cx; outp[1] = cy; outp[2] = cz; }
  for (int s = 1; s < NPOINT; ++s) {
    const v2f cxx = (v2f){cx, cx};
    const v2f cyy = (v2f){cy, cy};
    const v2f czz = (v2f){cz, cz};
    float bv = -1.0f;
    int bI = 0;
#pragma unroll
    for (int j = 0; j < 16; ++j) {
      v2f dx = px2[j] - cxx;            // v_pk_add_f32
      v2f dy = py2[j] - cyy;
      v2f dz = pz2[j] - czz;
      v2f xx = dx * dx;                 // v_pk_mul_f32
      v2f yy = dy * dy;
      v2f zz = dz * dz;
      v2f d = (xx + yy) + zz;           // contract off: exact np order
      float dmx = fminf(d2[j].x, d.x);  // no pk_min_f32 on CDNA: scalar
      float dmy = fminf(d2[j].y, d.y);
      d2[j].x = dmx;
      d2[j].y = dmy;
      if (dmx > bv) { bv = dmx; bI = 2 * j; }       // i ascending => n asc
      if (dmy > bv) { bv = dmy; bI = 2 * j + 1; }   // first-occurrence kept
    }
    int bi = tid + (bI << 8);           // global point index (n = tid + 256*i)
    // --- wave reduce, phase 1: max value (bv >= 0, f32 max) ---
    float m = bv;
    m = dpp_fmax_step<0x111>(m);        // row_shr:1
    m = dpp_fmax_step<0x112>(m);        // row_shr:2
    m = dpp_fmax_step<0x114>(m);        // row_shr:4
    m = dpp_fmax_step<0x118>(m);        // row_shr:8
    m = dpp_fmax_step<0x142>(m);        // row_bcast:15
    m = dpp_fmax_step<0x143>(m);        // row_bcast:31
    float Mw = __int_as_float(__builtin_amdgcn_readlane(__float_as_int(m), 63));
    // --- phase 2: among lanes at the max, min index via max(8191-bi) ---
    unsigned k2 = (bv == Mw) ? (unsigned)(8191 - bi) : 0u;
    k2 = dpp_umax_step<0x111>(k2);
    k2 = dpp_umax_step<0x112>(k2);
    k2 = dpp_umax_step<0x114>(k2);
    k2 = dpp_umax_step<0x118>(k2);
    k2 = dpp_umax_step<0x142>(k2);
    k2 = dpp_umax_step<0x143>(k2);
    unsigned K2 = (unsigned)__builtin_amdgcn_readlane((int)k2, 63);
    unsigned long long wkey =
        ((unsigned long long)__float_as_uint(Mw) << 32) | K2;
    if ((tid & 63) == 0) red[s & 1][tid >> 6] = wkey;
    __syncthreads();                    // the only barrier per iteration
    unsigned long long k0 = red[s & 1][0];
    unsigned long long k1 = red[s & 1][1];
    unsigned long long kB = red[s & 1][2];
    unsigned long long k3 = red[s & 1][3];
    unsigned long long ka = (k0 > k1) ? k0 : k1;
    unsigned long long kb = (kB > k3) ? kB : k3;
    unsigned long long km = (ka > kb) ? ka : kb;
    int gi = 8191 - (int)(unsigned)(km & 0xFFFFFFFFull);
    // block-uniform index -> SGPR -> s_load_dwordx4 (scalar cache path)
    int giu = __builtin_amdgcn_readfirstlane(gi);
    float4 cc = xp4[giu];
    cx = cc.x; cy = cc.y; cz = cc.z;
    if (tid == 0) { outp[3 * s] = cx; outp[3 * s + 1] = cy; outp[3 * s + 2] = cz; }
  }
}

// ---------------------------------------------------------------------------
// Ball query: one wave per center. Replicates the reference's expanded
// sq = |a|^2 + |b|^2 - 2 a.b (contract off) and first-32-by-index semantics.
// ---------------------------------------------------------------------------
__global__ __launch_bounds__(256) void bq_kernel(const float* __restrict__ xyz,
                                                 const float* __restrict__ new_xyz,
                                                 int* __restrict__ idx_out) {
#pragma clang fp contract(off)
  __shared__ int slots[4][NSAMPLE];
  const int tid = threadIdx.x;
  const int wv = tid >> 6, lane = tid & 63;
  const int gc = blockIdx.x * 4 + wv;   // global center 0..4095
  const int b = gc >> 10;
  const float* xp = xyz + (size_t)b * 3 * NPTS;
  const float* cp = new_xyz + (size_t)gc * 3;
  const float cx = cp[0], cy = cp[1], cz = cp[2];
  const float asq = (cx * cx + cy * cy) + cz * cz;
  int cnt = 0;
  for (int base = 0; base < NPTS; base += 64) {
    int n = base + lane;
    float x = xp[n], y = xp[NPTS + n], z = xp[2 * NPTS + n];
    float bsq = (x * x + y * y) + z * z;
    float ab = (x * cx + y * cy) + z * cz;
    float sq = (asq + bsq) - 2.0f * ab;
    bool inc = !(sq > 0.01f);           // same f32 threshold as reference
    unsigned long long mk = __ballot(inc);
    int pos = cnt + (int)__popcll(mk & ((1ull << lane) - 1ull));
    if (inc && pos < NSAMPLE) slots[wv][pos] = n;
    cnt += (int)__popcll(mk);
    if (cnt >= NSAMPLE) break;          // wave-uniform
  }
  __syncthreads();
  if (lane < NSAMPLE) {
    int first = slots[wv][0];           // >=1 hit guaranteed (center itself)
    int v = (lane < cnt) ? slots[wv][lane] : first;
    idx_out[(size_t)gc * NSAMPLE + lane] = v;
  }
}

// ---------------------------------------------------------------------------
// Setup (grid = 128 blocks): every block packs 256 points of the float4
// coord table xyz4[b][n] = (x,y,z,0); block 0 additionally transposes
// w3 -> w3t and folds BN (+bias) into per-channel scale/shift.
// ---------------------------------------------------------------------------
__global__ __launch_bounds__(256) void setup_kernel(
    const float* __restrict__ xyz, const float* __restrict__ w3,
    const float* __restrict__ b1, const float* __restrict__ g1, const float* __restrict__ t1,
    const float* __restrict__ m1, const float* __restrict__ v1,
    const float* __restrict__ b2, const float* __restrict__ g2, const float* __restrict__ t2,
    const float* __restrict__ m2, const float* __restrict__ v2,
    const float* __restrict__ b3, const float* __restrict__ g3, const float* __restrict__ t3,
    const float* __restrict__ m3, const float* __restrict__ v3,
    float4* __restrict__ xyz4, float* __restrict__ w3t, float* __restrict__ scsh) {
  int tid = threadIdx.x;
  int p = blockIdx.x * 256 + tid;       // 0..32767
  int bb = p >> 13, n = p & 8191;
  const float* src = xyz + (size_t)bb * 3 * NPTS;
  xyz4[p] = make_float4(src[n], src[NPTS + n], src[2 * NPTS + n], 0.f);
  if (blockIdx.x != 0) return;
  for (int i = tid; i < 8192; i += 256) {
    int o = i >> 6, c = i & 63;
    w3t[c * 128 + o] = w3[i];
  }
  if (tid < 64) {
    float s = g1[tid] / sqrtf(v1[tid] + 1e-5f);
    scsh[tid] = s;
    scsh[64 + tid] = (b1[tid] - m1[tid]) * s + t1[tid];
    float s2 = g2[tid] / sqrtf(v2[tid] + 1e-5f);
    scsh[128 + tid] = s2;
    scsh[192 + tid] = (b2[tid] - m2[tid]) * s2 + t2[tid];
  }
  if (tid < 128) {
    float s3 = g3[tid] / sqrtf(v3[tid] + 1e-5f);
    scsh[256 + tid] = s3;
    scsh[384 + tid] = (b3[tid] - m3[tid]) * s3 + t3[tid];
  }
}

// ---------------------------------------------------------------------------
// Fused gather + MLP(6->64->64->128, BN+ReLU) + max over 32 samples.
// Block = 256 threads = 8 centers x 32 samples. Activations live in one
// 64KB LDS buffer, XOR-swizzled at float4 granularity (conflict-free at the
// b128 bank floor). L1/L2 use (center,sample) mapping (own-row, no barrier);
// L3 uses (center,channel-lane) mapping so the k-loop folds into a register
// max (no cross-lane butterfly).
// ---------------------------------------------------------------------------
__global__ __launch_bounds__(256, 2) void mlp_kernel(
    const float* __restrict__ xyz, const float* __restrict__ points,
    const float* __restrict__ new_xyz, const int* __restrict__ idx,
    const float* __restrict__ w1, const float* __restrict__ w2,
    const float* __restrict__ w3t, const float* __restrict__ scsh,
    float* __restrict__ out) {
  __shared__ float act[256 * 64];       // exactly 64 KB -> 2 blocks/CU
  float4* act4 = (float4*)act;
  const int tid = threadIdx.x;
  const int s0 = blockIdx.x * 8;
  const int b = s0 >> 10;               // 8 | 1024 -> uniform per block
  const int g = tid >> 5;               // center within block
  const int k = tid & 31;               // sample (phase A) / channel lane (L3)
  const int gc = s0 + g;
  const float* xp = xyz + (size_t)b * 3 * NPTS;
  const float* pp = points + (size_t)b * 3 * NPTS;
  const float* cp = new_xyz + (size_t)gc * 3;
  const int n = idx[(size_t)gc * NSAMPLE + k];
  float f0 = xp[n] - cp[0];
  float f1 = xp[NPTS + n] - cp[1];
  float f2 = xp[2 * NPTS + n] - cp[2];
  float f3 = pp[n];
  float f4 = pp[NPTS + n];
  float f5 = pp[2 * NPTS + n];
  const float* sc1 = scsh;        const float* sh1 = scsh + 64;
  const float* sc2 = scsh + 128;  const float* sh2 = scsh + 192;
  const float* sc3 = scsh + 256;  const float* sh3 = scsh + 384;
  const int row = tid;

  // ---- L1: x1[o] = relu(bn(W1 @ f)) -> LDS (own row, swizzled float4) ----
#pragma unroll
  for (int oc = 0; oc < 16; ++oc) {
    float va[4];
#pragma unroll
    for (int jj = 0; jj < 4; ++jj) {
      int o = oc * 4 + jj;
      const float* wr = w1 + o * 6;     // wave-uniform -> scalar loads
      float a = f0 * wr[0] + f1 * wr[1] + f2 * wr[2] +
                f3 * wr[3] + f4 * wr[4] + f5 * wr[5];
      va[jj] = fmaxf(a * sc1[o] + sh1[o], 0.f);
    }
    act4[row * 16 + (oc ^ (row & 15))] = make_float4(va[0], va[1], va[2], va[3]);
  }

  // ---- L2: own-row contraction, 64 accumulators, uniform scalar weights ----
  float acc[64];
#pragma unroll
  for (int o = 0; o < 64; ++o) acc[o] = 0.f;
  for (int cc = 0; cc < 16; ++cc) {     // dynamic: LDS handles dynamic index
    float4 av = act4[row * 16 + (cc ^ (row & 15))];
#pragma unroll
    for (int o = 0; o < 64; ++o) {
      const float* wr = w2 + o * 64 + cc * 4;  // wave-uniform address
      acc[o] += av.x * wr[0] + av.y * wr[1] + av.z * wr[2] + av.w * wr[3];
    }
  }
  // bn+relu, overwrite own row with x2 (no cross-thread x1 readers)
#pragma unroll
  for (int oc = 0; oc < 16; ++oc) {
    float va[4];
#pragma unroll
    for (int jj = 0; jj < 4; ++jj) {
      int o = oc * 4 + jj;
      va[jj] = fmaxf(acc[o] * sc2[o] + sh2[o], 0.f);
    }
    act4[row * 16 + (oc ^ (row & 15))] = make_float4(va[0], va[1], va[2], va[3]);
  }
  __syncthreads();                      // x2 visible to whole block

  // ---- L3 + max over k: lane j owns channel o3 = p*32+j ----
  const int j = k;
  const int sb = gc & 1023;
  for (int p = 0; p < 4; ++p) {
    int o3 = p * 32 + j;
    float wreg[64];
#pragma unroll
    for (int c = 0; c < 64; ++c) wreg[c] = w3t[c * 128 + o3];  // coalesced
    float osc = sc3[o3], osh = sh3[o3];
    float vmax = 0.f;                   // post-relu values are >= 0
    for (int kk = 0; kk < 32; ++kk) {
      int r2 = g * 32 + kk;             // uniform within 32-lane group
      float a0 = 0.f, a1 = 0.f, a2 = 0.f, a3 = 0.f;
#pragma unroll
      for (int cc = 0; cc < 16; cc += 4) {
        float4 u0 = act4[r2 * 16 + ((cc + 0) ^ (r2 & 15))];  // broadcast b128
        float4 u1 = act4[r2 * 16 + ((cc + 1) ^ (r2 & 15))];
        float4 u2 = act4[r2 * 16 + ((cc + 2) ^ (r2 & 15))];
        float4 u3 = act4[r2 * 16 + ((cc + 3) ^ (r2 & 15))];
        a0 += u0.x * wreg[4*cc+0]  + u0.y * wreg[4*cc+1]  + u0.z * wreg[4*cc+2]  + u0.w * wreg[4*cc+3];
        a1 += u1.x * wreg[4*cc+4]  + u1.y * wreg[4*cc+5]  + u1.z * wreg[4*cc+6]  + u1.w * wreg[4*cc+7];
        a2 += u2.x * wreg[4*cc+8]  + u2.y * wreg[4*cc+9]  + u2.z * wreg[4*cc+10] + u2.w * wreg[4*cc+11];
        a3 += u3.x * wreg[4*cc+12] + u3.y * wreg[4*cc+13] + u3.z * wreg[4*cc+14] + u3.w * wreg[4*cc+15];
      }
      float x3 = (a0 + a1) + (a2 + a3);
      vmax = fmaxf(vmax, fmaxf(x3 * osc + osh, 0.f));
    }
    out[((size_t)b * 128 + o3) * 1024 + sb] = vmax;   // (B,128,1024)
  }
}

// ---------------------------------------------------------------------------
extern "C" void kernel_launch(void* const* d_in, const int* in_sizes, int n_in,
                              void* d_out, int out_size, void* d_ws, size_t ws_size,
                              hipStream_t stream) {
  (void)in_sizes; (void)n_in; (void)out_size; (void)ws_size;
  const float* xyz    = (const float*)d_in[0];
  const float* points = (const float*)d_in[1];
  const float* w1 = (const float*)d_in[2];
  const float* b1 = (const float*)d_in[3];
  const float* g1 = (const float*)d_in[4];
  const float* t1 = (const float*)d_in[5];
  const float* m1 = (const float*)d_in[6];
  const float* v1 = (const float*)d_in[7];
  const float* w2 = (const float*)d_in[8];
  const float* b2 = (const float*)d_in[9];
  const float* g2 = (const float*)d_in[10];
  const float* t2 = (const float*)d_in[11];
  const float* m2 = (const float*)d_in[12];
  const float* v2 = (const float*)d_in[13];
  const float* w3 = (const float*)d_in[14];
  const float* b3 = (const float*)d_in[15];
  const float* g3 = (const float*)d_in[16];
  const float* t3 = (const float*)d_in[17];
  const float* m3 = (const float*)d_in[18];
  const float* v3 = (const float*)d_in[19];

  float* wsf = (float*)d_ws;
  float* new_xyz = wsf;                         // 4*1024*3   = 12288 f
  int*   idx     = (int*)(wsf + 12288);         // 4*1024*32  = 131072 i
  float* w3t     = wsf + 12288 + 131072;        // 64*128     = 8192 f
  float* scsh    = w3t + 8192;                  // 512 f
  float4* xyz4   = (float4*)(scsh + 512);       // 4*8192 float4 = 512 KB
  float* out     = (float*)d_out;               // (4,128,1024) f32

  hipLaunchKernelGGL(setup_kernel, dim3(128), dim3(256), 0, stream,
                     xyz, w3, b1, g1, t1, m1, v1, b2, g2, t2, m2, v2,
                     b3, g3, t3, m3, v3, xyz4, w3t, scsh);
  hipLaunchKernelGGL(fps_kernel, dim3(4), dim3(256), 0, stream, xyz4, new_xyz);
  hipLaunchKernelGGL(bq_kernel, dim3(1024), dim3(256), 0, stream,
                     xyz, new_xyz, idx);
  hipLaunchKernelGGL(mlp_kernel, dim3(512), dim3(256), 0, stream,
                     xyz, points, new_xyz, idx, w1, w2, w3t, scsh, out);
}